// Round 7
// baseline (257.674 us; speedup 1.0000x reference)
//
#include <hip/hip_runtime.h>
#include <cstddef>
#include <cstdint>

// Problem constants (B=2, T=8 -> BT=16), L=512, D=1024, H=16, dh=64, MAX_REL=128
#define BTN 16
#define LL 512
#define DD 1024
#define NH 16
#define DH 64

using bf8 = __attribute__((ext_vector_type(8))) short;          // 8 bf16 (4 VGPRs), MFMA operand
using fx4 = __attribute__((ext_vector_type(4))) float;          // MFMA accumulator

__device__ __forceinline__ unsigned short f2bf(float f) {
  unsigned int u = __float_as_uint(f);
  u += 0x7FFFu + ((u >> 16) & 1u);   // RNE
  return (unsigned short)(u >> 16);
}

__device__ __forceinline__ fx4 mfma16(bf8 a, bf8 b, fx4 c) {
  return __builtin_amdgcn_mfma_f32_16x16x32_bf16(a, b, c, 0, 0, 0);
}

// async global->LDS, 16B/lane, dest = wave-uniform base + lane*16
__device__ __forceinline__ void gld_lds16(const void* g, void* l) {
  __builtin_amdgcn_global_load_lds((const __attribute__((address_space(1))) void*)g,
                                   (__attribute__((address_space(3))) void*)l, 16, 0, 0);
}

// ---------------- prep kernels ----------------

__global__ __launch_bounds__(256) void k_cvt(const float* __restrict__ src,
                                             unsigned short* __restrict__ dst) {
  const int i = blockIdx.x * 256 + threadIdx.x;
  const float4 v = ((const float4*)src)[i];
  ushort4 o;
  o.x = f2bf(v.x); o.y = f2bf(v.y); o.z = f2bf(v.z); o.w = f2bf(v.w);
  ((ushort4*)dst)[i] = o;
}

// src (R x C fp32, row-major) -> dst (C x R bf16). 32x32 LDS tile transpose.
__global__ __launch_bounds__(256) void k_trans(const float* __restrict__ src,
                                               unsigned short* __restrict__ dst,
                                               int R, int C) {
  __shared__ float t[32][33];
  const int tx = threadIdx.x & 31, ty = threadIdx.x >> 5;
  const int c0 = blockIdx.x * 32, r0 = blockIdx.y * 32;
  for (int i = ty; i < 32; i += 8)
    t[i][tx] = src[(size_t)(r0 + i) * C + c0 + tx];
  __syncthreads();
  for (int i = ty; i < 32; i += 8)
    dst[(size_t)(c0 + i) * R + r0 + tx] = f2bf(t[tx][i]);
}

// ---------------- GEMM core (C = A * B^T), A: Mx1024, B^T given as Nx1024 bf16 ----------------
// R4-PROVEN single-buffer structure (R6's 64KB double-buffer cut occupancy and regressed).
// 128x128 block tile, BK=64, 256 threads = 4 waves in 2x2 of 64x64.
// LDS tiles UNPADDED [128][64] for global_load_lds; bank spread via XOR swizzle:
// LDS slot (row, s) holds global 16B-segment s ^ (row & 7).

__device__ __forceinline__ void gemm_core(const unsigned short* __restrict__ A,
                                          const unsigned short* __restrict__ B,
                                          unsigned short* Al, unsigned short* Bl,
                                          int m0, int n0, fx4 (&acc)[4][4]) {
  const int tid = threadIdx.x;
  const int lane = tid & 63, wave = tid >> 6;
  const int quad = lane >> 4, l16 = lane & 15;
  const int wr = (wave >> 1) * 64, wc = (wave & 1) * 64;
  const int rl = lane >> 3;                 // row within 8-row group
  const int sg = (lane & 7) ^ rl;           // swizzled global segment for this LDS slot
  const unsigned short* pa = A + (size_t)(m0 + wave * 32 + rl) * 1024 + sg * 8;
  const unsigned short* pb = B + (size_t)(n0 + wave * 32 + rl) * 1024 + sg * 8;
  unsigned short* la = Al + wave * 2048;    // 32 rows * 64 elems
  unsigned short* lb = Bl + wave * 2048;

  for (int kt = 0; kt < 1024; kt += 64) {
    __syncthreads();
#pragma unroll
    for (int i = 0; i < 4; ++i) {
      gld_lds16(pa + kt + i * 8 * 1024, la + i * 512);
      gld_lds16(pb + kt + i * 8 * 1024, lb + i * 512);
    }
    __syncthreads();
#pragma unroll
    for (int kk = 0; kk < 2; ++kk) {
      bf8 av[4], bv[4];
#pragma unroll
      for (int mi = 0; mi < 4; ++mi) {
        const int row = wr + mi * 16 + l16;
        av[mi] = *(const bf8*)(Al + row * 64 + (((kk * 4 + quad) ^ (l16 & 7)) * 8));
      }
#pragma unroll
      for (int nj = 0; nj < 4; ++nj) {
        const int row = wc + nj * 16 + l16;
        bv[nj] = *(const bf8*)(Bl + row * 64 + (((kk * 4 + quad) ^ (l16 & 7)) * 8));
      }
#pragma unroll
      for (int mi = 0; mi < 4; ++mi)
#pragma unroll
        for (int nj = 0; nj < 4; ++nj)
          acc[mi][nj] = mfma16(av[mi], bv[nj], acc[mi][nj]);
    }
  }
}

// QKV GEMM: x_bf (8192x1024) @ w_qkvT (3072x1024)^T -> scatter into q/k (bh-major) and vT.
__global__ __launch_bounds__(256, 4) void k_gemm_qkv(const unsigned short* __restrict__ xbf,
                                                     const unsigned short* __restrict__ wT,
                                                     unsigned short* __restrict__ qws,
                                                     unsigned short* __restrict__ kws,
                                                     unsigned short* __restrict__ vws) {
  __shared__ unsigned short Al[128 * 64];
  __shared__ unsigned short Bl[128 * 64];
  const int m0 = blockIdx.y * 128, n0 = blockIdx.x * 128;
  fx4 acc[4][4];
  const fx4 zero = {0.f, 0.f, 0.f, 0.f};
#pragma unroll
  for (int mi = 0; mi < 4; ++mi)
#pragma unroll
    for (int nj = 0; nj < 4; ++nj) acc[mi][nj] = zero;

  gemm_core(xbf, wT, Al, Bl, m0, n0, acc);

  const int lane = threadIdx.x & 63, wave = threadIdx.x >> 6;
  const int quad = lane >> 4, l16 = lane & 15;
  const int wr = (wave >> 1) * 64, wc = (wave & 1) * 64;
  const int which = n0 >> 10;  // 0=q, 1=k, 2=v (block-uniform: 1024 % 128 == 0)
#pragma unroll
  for (int mi = 0; mi < 4; ++mi)
#pragma unroll
    for (int nj = 0; nj < 4; ++nj) {
      const int gn = n0 + wc + nj * 16 + l16;
      const int rem = gn & 1023;
      const int hh = rem >> 6, dd = rem & 63;
#pragma unroll
      for (int rr = 0; rr < 4; ++rr) {
        const int gm = m0 + wr + mi * 16 + quad * 4 + rr;
        const int bth = gm >> 9, ll = gm & 511;
        const unsigned short v = f2bf(acc[mi][nj][rr]);
        const size_t bhh = (size_t)(bth * NH + hh);
        if (which == 0)      qws[(bhh * LL + ll) * DH + dd] = v;
        else if (which == 1) kws[(bhh * LL + ll) * DH + dd] = v;
        else                 vws[(bhh * DH + dd) * LL + ll] = v;  // V transposed [bh][d][l]
      }
    }
}

// Out projection: o_bf (8192x1024) @ w_outT (1024x1024)^T + b_out -> fp32 out.
__global__ __launch_bounds__(256, 4) void k_gemm_out(const unsigned short* __restrict__ obf,
                                                     const unsigned short* __restrict__ wT,
                                                     const float* __restrict__ bout,
                                                     float* __restrict__ out) {
  __shared__ unsigned short Al[128 * 64];
  __shared__ unsigned short Bl[128 * 64];
  const int m0 = blockIdx.y * 128, n0 = blockIdx.x * 128;
  fx4 acc[4][4];
  const fx4 zero = {0.f, 0.f, 0.f, 0.f};
#pragma unroll
  for (int mi = 0; mi < 4; ++mi)
#pragma unroll
    for (int nj = 0; nj < 4; ++nj) acc[mi][nj] = zero;

  gemm_core(obf, wT, Al, Bl, m0, n0, acc);

  const int lane = threadIdx.x & 63, wave = threadIdx.x >> 6;
  const int quad = lane >> 4, l16 = lane & 15;
  const int wr = (wave >> 1) * 64, wc = (wave & 1) * 64;
#pragma unroll
  for (int nj = 0; nj < 4; ++nj) {
    const int gn = n0 + wc + nj * 16 + l16;
    const float bb = bout[gn];
#pragma unroll
    for (int mi = 0; mi < 4; ++mi)
#pragma unroll
      for (int rr = 0; rr < 4; ++rr) {
        const int gm = m0 + wr + mi * 16 + quad * 4 + rr;
        out[(size_t)gm * 1024 + gn] = acc[mi][nj][rr] + bb;
      }
  }
}

// ---------------- flash attention with relative-position bias ----------------
// R7: TRANSPOSED-SCORE formulation. S^T = K·Q^T (swapped MFMA operands, identical
// fragment reads). C-layout now has q on lanes (l16) and s on regs (quad*4+rr), so:
//   - P writes to LDS pack 4 s-contiguous bf16 -> ds_write_b64 (16 vs 64 instrs)
//   - PV is O^T = V^T·P^T: A-frag from Vl (unchanged reads), B-frag from Pl (b128)
//   - row-sums l = mfma(ones, P^T) reusing the PV B-fragment; uniform per lane
//   - O epilogue packs 4 d-contiguous bf16 -> 8B global stores (8 vs 32 instrs)
// Schedule (R4/R6-proven): barrier drains K(st) prefetch; stage V + barrier;
// QK -> bias/exp -> P; P-barrier; issue K(st+1) overlapping PV.

#define LDP 136

__global__ __launch_bounds__(256, 2) void k_attn(const unsigned short* __restrict__ qw,
                                                 const unsigned short* __restrict__ kw,
                                                 const unsigned short* __restrict__ vw,
                                                 const float* __restrict__ rel,
                                                 unsigned short* __restrict__ ow) {
  __shared__ unsigned short Kl[128 * 64];
  __shared__ unsigned short Vl[64 * 128];
  __shared__ unsigned short Pl[128 * LDP];
  __shared__ float rell[255];

  const int tid = threadIdx.x;
  const int wave = tid >> 6, lane = tid & 63;
  const int quad = lane >> 4, l16 = lane & 15;
  const int bh = blockIdx.x >> 2, qt = blockIdx.x & 3;
  const int bth = bh >> 4, h = bh & 15;
  const int W = wave * 32;

  if (tid < 255) rell[tid] = rel[tid * NH + h];

  // Q fragments (per-lane mapping identical for A- and B-operand use): row l16, k=quad*8+j
  bf8 qf[2][2];
  const size_t qbase = (size_t)bh * (LL * DH) + (size_t)(qt * 128 + W) * DH;
#pragma unroll
  for (int mi = 0; mi < 2; ++mi)
#pragma unroll
    for (int kk = 0; kk < 2; ++kk)
      qf[mi][kk] = *(const bf8*)(qw + qbase + (mi * 16 + l16) * DH + kk * 32 + quad * 8);

  fx4 O2[4][2];   // O^T tiles: [no over d][mi over q]
  fx4 lS[2];      // row sums per q (uniform over regs)
  const fx4 zero = {0.f, 0.f, 0.f, 0.f};
#pragma unroll
  for (int mi = 0; mi < 2; ++mi) {
    lS[mi] = zero;
#pragma unroll
    for (int no = 0; no < 4; ++no) O2[no][mi] = zero;
  }

  // staging lane mappings
  const int rk = lane >> 3, sgk = (lane & 7) ^ rk;     // K tile: 8 rows x 8 segs / instr
  const int rv = lane >> 4;                            // V tile: 4 rows x 16 segs / instr
  const unsigned short* kbase = kw + (size_t)bh * (LL * DH) + (size_t)(W + rk) * 64 + sgk * 8;
  const unsigned short* vbase = vw + (size_t)bh * (DH * LL);
  unsigned short* kdst = Kl + wave * 2048;
  unsigned short* vdst = Vl + wave * 2048;

  // prologue: stage K(0) async
#pragma unroll
  for (int i = 0; i < 4; ++i)
    gld_lds16(kbase + (size_t)(i * 8) * 64, kdst + i * 512);

  for (int st = 0; st < 4; ++st) {
    __syncthreads();  // drains K(st); prior PV done (Vl free)
    // stage V(st)
#pragma unroll
    for (int i = 0; i < 4; ++i) {
      const int rowv = wave * 16 + i * 4 + rv;
      const int sgv = (lane & 15) ^ (rowv & 15);
      gld_lds16(vbase + (size_t)rowv * 512 + st * 128 + sgv * 8, vdst + i * 512);
    }
    __syncthreads();  // drains V(st)

    // S^T = K Q^T  (tiles [mi over q][nj over s]; C-layout: row=s=quad*4+rr, col=q=l16)
    fx4 S[2][8];
#pragma unroll
    for (int mi = 0; mi < 2; ++mi)
#pragma unroll
      for (int nj = 0; nj < 8; ++nj) S[mi][nj] = zero;
#pragma unroll
    for (int kk = 0; kk < 2; ++kk) {
      bf8 ak[8];
#pragma unroll
      for (int nj = 0; nj < 8; ++nj) {
        const int row = nj * 16 + l16;
        ak[nj] = *(const bf8*)(Kl + row * 64 + (((kk * 4 + quad) ^ (l16 & 7)) * 8));
      }
#pragma unroll
      for (int mi = 0; mi < 2; ++mi)
#pragma unroll
        for (int nj = 0; nj < 8; ++nj)
          S[mi][nj] = mfma16(ak[nj], qf[mi][kk], S[mi][nj]);
    }

    // ---- bias + exp (fixed-max softmax), specialized by tile distance ----
    // q = qt*128 + W + mi*16 + l16 ; s = st*128 + nj*16 + quad*4 + rr
    const int delta = qt - st;
    if (delta >= 2 || delta <= -2) {
      const float cb = (delta >= 2) ? rell[254] : rell[0];
#pragma unroll
      for (int mi = 0; mi < 2; ++mi)
#pragma unroll
        for (int nj = 0; nj < 8; ++nj)
#pragma unroll
          for (int rr = 0; rr < 4; ++rr)
            S[mi][nj][rr] = __expf(fmaf(S[mi][nj][rr], 0.125f, cb));
    } else if (delta == 0) {
#pragma unroll
      for (int mi = 0; mi < 2; ++mi) {
        const int base = W + mi * 16 + l16 - quad * 4 + 127;
#pragma unroll
        for (int nj = 0; nj < 8; ++nj) {
          const int bmn = base - nj * 16;
#pragma unroll
          for (int rr = 0; rr < 4; ++rr)
            S[mi][nj][rr] = __expf(fmaf(S[mi][nj][rr], 0.125f, rell[bmn - rr]));
        }
      }
    } else {  // |delta| == 1
#pragma unroll
      for (int mi = 0; mi < 2; ++mi) {
        const int base = delta * 128 + W + mi * 16 + l16 - quad * 4 + 127;
#pragma unroll
        for (int nj = 0; nj < 8; ++nj) {
          const int bmn = base - nj * 16;
#pragma unroll
          for (int rr = 0; rr < 4; ++rr) {
            int idx = bmn - rr;
            idx = idx < 0 ? 0 : (idx > 254 ? 254 : idx);
            S[mi][nj][rr] = __expf(fmaf(S[mi][nj][rr], 0.125f, rell[idx]));
          }
        }
      }
    }

    // P -> LDS row-major [q][s]; 4 rr values are s-contiguous -> packed 8B writes
#pragma unroll
    for (int mi = 0; mi < 2; ++mi) {
      const int rowq = W + mi * 16 + l16;
#pragma unroll
      for (int nj = 0; nj < 8; ++nj) {
        ushort4 p4;
        p4.x = f2bf(S[mi][nj][0]); p4.y = f2bf(S[mi][nj][1]);
        p4.z = f2bf(S[mi][nj][2]); p4.w = f2bf(S[mi][nj][3]);
        *(ushort4*)(Pl + rowq * LDP + nj * 16 + quad * 4) = p4;
      }
    }
    __syncthreads();  // Pl published; all Kl reads complete

    // prefetch K(st+1) — overlaps the PV phase (PV touches only Vl/Pl)
    if (st < 3) {
#pragma unroll
      for (int i = 0; i < 4; ++i)
        gld_lds16(kbase + (size_t)((st + 1) * 128 + i * 8) * 64, kdst + i * 512);
    }

    // O^T += V^T P^T ; lS = mfma(ones, P^T)   (K-dim = 128 s, 4 MFMA k-steps)
    const bf8 ones = {0x3F80, 0x3F80, 0x3F80, 0x3F80, 0x3F80, 0x3F80, 0x3F80, 0x3F80};
#pragma unroll
    for (int kk = 0; kk < 4; ++kk) {
      bf8 bp[2], av[4];
#pragma unroll
      for (int mi = 0; mi < 2; ++mi)
        bp[mi] = *(const bf8*)(Pl + (W + mi * 16 + l16) * LDP + kk * 32 + quad * 8);
#pragma unroll
      for (int no = 0; no < 4; ++no) {
        const int row = no * 16 + l16;
        av[no] = *(const bf8*)(Vl + row * 128 + (((kk * 4 + quad) ^ l16) * 8));
      }
#pragma unroll
      for (int no = 0; no < 4; ++no)
#pragma unroll
        for (int mi = 0; mi < 2; ++mi)
          O2[no][mi] = mfma16(av[no], bp[mi], O2[no][mi]);
#pragma unroll
      for (int mi = 0; mi < 2; ++mi)
        lS[mi] = mfma16(ones, bp[mi], lS[mi]);
    }
  }

  // normalize and store O^T (C-layout: row=d=quad*4+rr contiguous, col=q=l16) -> packed 8B
#pragma unroll
  for (int mi = 0; mi < 2; ++mi) {
    const float inv = __builtin_amdgcn_rcpf(lS[mi][0]);  // all regs equal (ones rows)
    const int gm = bth * LL + qt * 128 + W + mi * 16 + l16;
    const size_t rowbase = (size_t)gm * DD + h * DH + quad * 4;
#pragma unroll
    for (int no = 0; no < 4; ++no) {
      ushort4 o4;
      o4.x = f2bf(O2[no][mi][0] * inv); o4.y = f2bf(O2[no][mi][1] * inv);
      o4.z = f2bf(O2[no][mi][2] * inv); o4.w = f2bf(O2[no][mi][3] * inv);
      *(ushort4*)(ow + rowbase + no * 16) = o4;
    }
  }
}

// ---------------- launch ----------------

extern "C" void kernel_launch(void* const* d_in, const int* in_sizes, int n_in,
                              void* d_out, int out_size, void* d_ws, size_t ws_size,
                              hipStream_t stream) {
  const float* x    = (const float*)d_in[0];  // (16, 512, 1024)
  const float* wqkv = (const float*)d_in[1];  // (1024, 3072)
  const float* rel  = (const float*)d_in[2];  // (255, 16)
  const float* wout = (const float*)d_in[3];  // (1024, 1024)
  const float* bout = (const float*)d_in[4];  // (1024,)
  float* out = (float*)d_out;

  char* ws = (char*)d_ws;
  unsigned short* xbf   = (unsigned short*)(ws);             // 16 MB  x as bf16 [8192][1024]
  unsigned short* wqkvT = (unsigned short*)(ws + 16777216);  //  6 MB  [3072][1024]
  unsigned short* woutT = (unsigned short*)(ws + 23068672);  //  2 MB  [1024][1024]
  unsigned short* qws   = (unsigned short*)(ws + 25165824);  // 16 MB  [256 bh][512][64]
  unsigned short* kws   = (unsigned short*)(ws + 41943040);  // 16 MB  [256 bh][512][64]
  unsigned short* vws   = (unsigned short*)(ws + 58720256);  // 16 MB  [256 bh][64][512]  (transposed)
  unsigned short* ows   = (unsigned short*)(ws + 75497472);  // 16 MB  [8192][1024]

  k_cvt<<<dim3(8192), dim3(256), 0, stream>>>(x, xbf);
  k_trans<<<dim3(96, 32), dim3(256), 0, stream>>>(wqkv, wqkvT, 1024, 3072);
  k_trans<<<dim3(32, 32), dim3(256), 0, stream>>>(wout, woutT, 1024, 1024);
  k_gemm_qkv<<<dim3(24, 64), dim3(256), 0, stream>>>(xbf, wqkvT, qws, kws, vws);
  k_attn<<<dim3(1024), dim3(256), 0, stream>>>(qws, kws, vws, rel, ows);
  k_gemm_out<<<dim3(8, 64), dim3(256), 0, stream>>>(ows, woutT, bout, out);
}

// Round 8
// 253.063 us; speedup vs baseline: 1.0182x; 1.0182x over previous
//
#include <hip/hip_runtime.h>
#include <cstddef>
#include <cstdint>

// Problem constants (B=2, T=8 -> BT=16), L=512, D=1024, H=16, dh=64, MAX_REL=128
#define BTN 16
#define LL 512
#define DD 1024
#define NH 16
#define DH 64

using bf8 = __attribute__((ext_vector_type(8))) short;          // 8 bf16 (4 VGPRs), MFMA operand
using fx4 = __attribute__((ext_vector_type(4))) float;          // MFMA accumulator

__device__ __forceinline__ unsigned short f2bf(float f) {
  unsigned int u = __float_as_uint(f);
  u += 0x7FFFu + ((u >> 16) & 1u);   // RNE
  return (unsigned short)(u >> 16);
}

__device__ __forceinline__ fx4 mfma16(bf8 a, bf8 b, fx4 c) {
  return __builtin_amdgcn_mfma_f32_16x16x32_bf16(a, b, c, 0, 0, 0);
}

// async global->LDS, 16B/lane, dest = wave-uniform base + lane*16
__device__ __forceinline__ void gld_lds16(const void* g, void* l) {
  __builtin_amdgcn_global_load_lds((const __attribute__((address_space(1))) void*)g,
                                   (__attribute__((address_space(3))) void*)l, 16, 0, 0);
}

// ---------------- prep kernels ----------------

__global__ __launch_bounds__(256) void k_cvt(const float* __restrict__ src,
                                             unsigned short* __restrict__ dst) {
  const int i = blockIdx.x * 256 + threadIdx.x;
  const float4 v = ((const float4*)src)[i];
  ushort4 o;
  o.x = f2bf(v.x); o.y = f2bf(v.y); o.z = f2bf(v.z); o.w = f2bf(v.w);
  ((ushort4*)dst)[i] = o;
}

// src (R x C fp32, row-major) -> dst (C x R bf16). 32x32 LDS tile transpose.
__global__ __launch_bounds__(256) void k_trans(const float* __restrict__ src,
                                               unsigned short* __restrict__ dst,
                                               int R, int C) {
  __shared__ float t[32][33];
  const int tx = threadIdx.x & 31, ty = threadIdx.x >> 5;
  const int c0 = blockIdx.x * 32, r0 = blockIdx.y * 32;
  for (int i = ty; i < 32; i += 8)
    t[i][tx] = src[(size_t)(r0 + i) * C + c0 + tx];
  __syncthreads();
  for (int i = ty; i < 32; i += 8)
    dst[(size_t)(c0 + i) * R + r0 + tx] = f2bf(t[tx][i]);
}

// ---------------- GEMM core (C = A * B^T), A: Mx1024, B^T given as Nx1024 bf16 ----------------
// R4-PROVEN single-buffer structure. 128x128 block tile, BK=64, 4 waves in 2x2 of 64x64.
// LDS tiles UNPADDED [128][64] for global_load_lds; bank spread via XOR swizzle:
// LDS slot (row, s) holds global 16B-segment s ^ (row & 7).

__device__ __forceinline__ void gemm_core(const unsigned short* __restrict__ A,
                                          const unsigned short* __restrict__ B,
                                          unsigned short* Al, unsigned short* Bl,
                                          int m0, int n0, fx4 (&acc)[4][4]) {
  const int tid = threadIdx.x;
  const int lane = tid & 63, wave = tid >> 6;
  const int quad = lane >> 4, l16 = lane & 15;
  const int wr = (wave >> 1) * 64, wc = (wave & 1) * 64;
  const int rl = lane >> 3;                 // row within 8-row group
  const int sg = (lane & 7) ^ rl;           // swizzled global segment for this LDS slot
  const unsigned short* pa = A + (size_t)(m0 + wave * 32 + rl) * 1024 + sg * 8;
  const unsigned short* pb = B + (size_t)(n0 + wave * 32 + rl) * 1024 + sg * 8;
  unsigned short* la = Al + wave * 2048;    // 32 rows * 64 elems
  unsigned short* lb = Bl + wave * 2048;

  for (int kt = 0; kt < 1024; kt += 64) {
    __syncthreads();
#pragma unroll
    for (int i = 0; i < 4; ++i) {
      gld_lds16(pa + kt + i * 8 * 1024, la + i * 512);
      gld_lds16(pb + kt + i * 8 * 1024, lb + i * 512);
    }
    __syncthreads();
#pragma unroll
    for (int kk = 0; kk < 2; ++kk) {
      bf8 av[4], bv[4];
#pragma unroll
      for (int mi = 0; mi < 4; ++mi) {
        const int row = wr + mi * 16 + l16;
        av[mi] = *(const bf8*)(Al + row * 64 + (((kk * 4 + quad) ^ (l16 & 7)) * 8));
      }
#pragma unroll
      for (int nj = 0; nj < 4; ++nj) {
        const int row = wc + nj * 16 + l16;
        bv[nj] = *(const bf8*)(Bl + row * 64 + (((kk * 4 + quad) ^ (l16 & 7)) * 8));
      }
#pragma unroll
      for (int mi = 0; mi < 4; ++mi)
#pragma unroll
        for (int nj = 0; nj < 4; ++nj)
          acc[mi][nj] = mfma16(av[mi], bv[nj], acc[mi][nj]);
    }
  }
}

// QKV GEMM: x_bf (8192x1024) @ w_qkvT (3072x1024)^T -> scatter into q/k (bh-major) and vT.
__global__ __launch_bounds__(256, 4) void k_gemm_qkv(const unsigned short* __restrict__ xbf,
                                                     const unsigned short* __restrict__ wT,
                                                     unsigned short* __restrict__ qws,
                                                     unsigned short* __restrict__ kws,
                                                     unsigned short* __restrict__ vws) {
  __shared__ unsigned short Al[128 * 64];
  __shared__ unsigned short Bl[128 * 64];
  const int m0 = blockIdx.y * 128, n0 = blockIdx.x * 128;
  fx4 acc[4][4];
  const fx4 zero = {0.f, 0.f, 0.f, 0.f};
#pragma unroll
  for (int mi = 0; mi < 4; ++mi)
#pragma unroll
    for (int nj = 0; nj < 4; ++nj) acc[mi][nj] = zero;

  gemm_core(xbf, wT, Al, Bl, m0, n0, acc);

  const int lane = threadIdx.x & 63, wave = threadIdx.x >> 6;
  const int quad = lane >> 4, l16 = lane & 15;
  const int wr = (wave >> 1) * 64, wc = (wave & 1) * 64;
  const int which = n0 >> 10;  // 0=q, 1=k, 2=v (block-uniform: 1024 % 128 == 0)
#pragma unroll
  for (int mi = 0; mi < 4; ++mi)
#pragma unroll
    for (int nj = 0; nj < 4; ++nj) {
      const int gn = n0 + wc + nj * 16 + l16;
      const int rem = gn & 1023;
      const int hh = rem >> 6, dd = rem & 63;
#pragma unroll
      for (int rr = 0; rr < 4; ++rr) {
        const int gm = m0 + wr + mi * 16 + quad * 4 + rr;
        const int bth = gm >> 9, ll = gm & 511;
        const unsigned short v = f2bf(acc[mi][nj][rr]);
        const size_t bhh = (size_t)(bth * NH + hh);
        if (which == 0)      qws[(bhh * LL + ll) * DH + dd] = v;
        else if (which == 1) kws[(bhh * LL + ll) * DH + dd] = v;
        else                 vws[(bhh * DH + dd) * LL + ll] = v;  // V transposed [bh][d][l]
      }
    }
}

// Out projection: o_bf (8192x1024) @ w_outT (1024x1024)^T + b_out -> fp32 out.
__global__ __launch_bounds__(256, 4) void k_gemm_out(const unsigned short* __restrict__ obf,
                                                     const unsigned short* __restrict__ wT,
                                                     const float* __restrict__ bout,
                                                     float* __restrict__ out) {
  __shared__ unsigned short Al[128 * 64];
  __shared__ unsigned short Bl[128 * 64];
  const int m0 = blockIdx.y * 128, n0 = blockIdx.x * 128;
  fx4 acc[4][4];
  const fx4 zero = {0.f, 0.f, 0.f, 0.f};
#pragma unroll
  for (int mi = 0; mi < 4; ++mi)
#pragma unroll
    for (int nj = 0; nj < 4; ++nj) acc[mi][nj] = zero;

  gemm_core(obf, wT, Al, Bl, m0, n0, acc);

  const int lane = threadIdx.x & 63, wave = threadIdx.x >> 6;
  const int quad = lane >> 4, l16 = lane & 15;
  const int wr = (wave >> 1) * 64, wc = (wave & 1) * 64;
#pragma unroll
  for (int nj = 0; nj < 4; ++nj) {
    const int gn = n0 + wc + nj * 16 + l16;
    const float bb = bout[gn];
#pragma unroll
    for (int mi = 0; mi < 4; ++mi)
#pragma unroll
      for (int rr = 0; rr < 4; ++rr) {
        const int gm = m0 + wr + mi * 16 + quad * 4 + rr;
        out[(size_t)gm * 1024 + gn] = acc[mi][nj][rr] + bb;
      }
  }
}

// ---------------- flash attention with relative-position bias ----------------
// Transposed-score formulation (R7): S^T = K·Q^T, PV as O^T = V^T·P^T, packed 8B P/O I/O.
// R8: (1) XCD-aware block relabeling: bh = blockIdx&255, qt = blockIdx>>8 — the 4 q-tiles
// of one head land on the SAME XCD (256 % 8 == 0), so K/V are fetched to that XCD's L2
// once instead of 4 XCDs separately. (2) Pl stride 136->140: write bank = 6*l16+2*quad
// mod 32 -> max 2-way (free) instead of 4-way.

#define LDP 140

__global__ __launch_bounds__(256, 2) void k_attn(const unsigned short* __restrict__ qw,
                                                 const unsigned short* __restrict__ kw,
                                                 const unsigned short* __restrict__ vw,
                                                 const float* __restrict__ rel,
                                                 unsigned short* __restrict__ ow) {
  __shared__ unsigned short Kl[128 * 64];
  __shared__ unsigned short Vl[64 * 128];
  __shared__ unsigned short Pl[128 * LDP];
  __shared__ float rell[255];

  const int tid = threadIdx.x;
  const int wave = tid >> 6, lane = tid & 63;
  const int quad = lane >> 4, l16 = lane & 15;
  const int bh = blockIdx.x & 255, qt = blockIdx.x >> 8;   // XCD co-location of a head's tiles
  const int bth = bh >> 4, h = bh & 15;
  const int W = wave * 32;

  if (tid < 255) rell[tid] = rel[tid * NH + h];

  // Q fragments (per-lane mapping identical for A- and B-operand use): row l16, k=quad*8+j
  bf8 qf[2][2];
  const size_t qbase = (size_t)bh * (LL * DH) + (size_t)(qt * 128 + W) * DH;
#pragma unroll
  for (int mi = 0; mi < 2; ++mi)
#pragma unroll
    for (int kk = 0; kk < 2; ++kk)
      qf[mi][kk] = *(const bf8*)(qw + qbase + (mi * 16 + l16) * DH + kk * 32 + quad * 8);

  fx4 O2[4][2];   // O^T tiles: [no over d][mi over q]
  fx4 lS[2];      // row sums per q (uniform over regs)
  const fx4 zero = {0.f, 0.f, 0.f, 0.f};
#pragma unroll
  for (int mi = 0; mi < 2; ++mi) {
    lS[mi] = zero;
#pragma unroll
    for (int no = 0; no < 4; ++no) O2[no][mi] = zero;
  }

  // staging lane mappings
  const int rk = lane >> 3, sgk = (lane & 7) ^ rk;     // K tile: 8 rows x 8 segs / instr
  const int rv = lane >> 4;                            // V tile: 4 rows x 16 segs / instr
  const unsigned short* kbase = kw + (size_t)bh * (LL * DH) + (size_t)(W + rk) * 64 + sgk * 8;
  const unsigned short* vbase = vw + (size_t)bh * (DH * LL);
  unsigned short* kdst = Kl + wave * 2048;
  unsigned short* vdst = Vl + wave * 2048;

  // prologue: stage K(0) async
#pragma unroll
  for (int i = 0; i < 4; ++i)
    gld_lds16(kbase + (size_t)(i * 8) * 64, kdst + i * 512);

  for (int st = 0; st < 4; ++st) {
    __syncthreads();  // drains K(st); prior PV done (Vl free)
    // stage V(st)
#pragma unroll
    for (int i = 0; i < 4; ++i) {
      const int rowv = wave * 16 + i * 4 + rv;
      const int sgv = (lane & 15) ^ (rowv & 15);
      gld_lds16(vbase + (size_t)rowv * 512 + st * 128 + sgv * 8, vdst + i * 512);
    }
    __syncthreads();  // drains V(st)

    // S^T = K Q^T  (tiles [mi over q][nj over s]; C-layout: row=s=quad*4+rr, col=q=l16)
    fx4 S[2][8];
#pragma unroll
    for (int mi = 0; mi < 2; ++mi)
#pragma unroll
      for (int nj = 0; nj < 8; ++nj) S[mi][nj] = zero;
#pragma unroll
    for (int kk = 0; kk < 2; ++kk) {
      bf8 ak[8];
#pragma unroll
      for (int nj = 0; nj < 8; ++nj) {
        const int row = nj * 16 + l16;
        ak[nj] = *(const bf8*)(Kl + row * 64 + (((kk * 4 + quad) ^ (l16 & 7)) * 8));
      }
#pragma unroll
      for (int mi = 0; mi < 2; ++mi)
#pragma unroll
        for (int nj = 0; nj < 8; ++nj)
          S[mi][nj] = mfma16(ak[nj], qf[mi][kk], S[mi][nj]);
    }

    // ---- bias + exp (fixed-max softmax), specialized by tile distance ----
    // q = qt*128 + W + mi*16 + l16 ; s = st*128 + nj*16 + quad*4 + rr
    const int delta = qt - st;
    if (delta >= 2 || delta <= -2) {
      const float cb = (delta >= 2) ? rell[254] : rell[0];
#pragma unroll
      for (int mi = 0; mi < 2; ++mi)
#pragma unroll
        for (int nj = 0; nj < 8; ++nj)
#pragma unroll
          for (int rr = 0; rr < 4; ++rr)
            S[mi][nj][rr] = __expf(fmaf(S[mi][nj][rr], 0.125f, cb));
    } else if (delta == 0) {
#pragma unroll
      for (int mi = 0; mi < 2; ++mi) {
        const int base = W + mi * 16 + l16 - quad * 4 + 127;
#pragma unroll
        for (int nj = 0; nj < 8; ++nj) {
          const int bmn = base - nj * 16;
#pragma unroll
          for (int rr = 0; rr < 4; ++rr)
            S[mi][nj][rr] = __expf(fmaf(S[mi][nj][rr], 0.125f, rell[bmn - rr]));
        }
      }
    } else {  // |delta| == 1
#pragma unroll
      for (int mi = 0; mi < 2; ++mi) {
        const int base = delta * 128 + W + mi * 16 + l16 - quad * 4 + 127;
#pragma unroll
        for (int nj = 0; nj < 8; ++nj) {
          const int bmn = base - nj * 16;
#pragma unroll
          for (int rr = 0; rr < 4; ++rr) {
            int idx = bmn - rr;
            idx = idx < 0 ? 0 : (idx > 254 ? 254 : idx);
            S[mi][nj][rr] = __expf(fmaf(S[mi][nj][rr], 0.125f, rell[idx]));
          }
        }
      }
    }

    // P -> LDS row-major [q][s]; 4 rr values are s-contiguous -> packed 8B writes
#pragma unroll
    for (int mi = 0; mi < 2; ++mi) {
      const int rowq = W + mi * 16 + l16;
#pragma unroll
      for (int nj = 0; nj < 8; ++nj) {
        ushort4 p4;
        p4.x = f2bf(S[mi][nj][0]); p4.y = f2bf(S[mi][nj][1]);
        p4.z = f2bf(S[mi][nj][2]); p4.w = f2bf(S[mi][nj][3]);
        *(ushort4*)(Pl + rowq * LDP + nj * 16 + quad * 4) = p4;
      }
    }
    __syncthreads();  // Pl published; all Kl reads complete

    // prefetch K(st+1) — overlaps the PV phase (PV touches only Vl/Pl)
    if (st < 3) {
#pragma unroll
      for (int i = 0; i < 4; ++i)
        gld_lds16(kbase + (size_t)((st + 1) * 128 + i * 8) * 64, kdst + i * 512);
    }

    // O^T += V^T P^T ; lS = mfma(ones, P^T)   (K-dim = 128 s, 4 MFMA k-steps)
    const bf8 ones = {0x3F80, 0x3F80, 0x3F80, 0x3F80, 0x3F80, 0x3F80, 0x3F80, 0x3F80};
#pragma unroll
    for (int kk = 0; kk < 4; ++kk) {
      bf8 bp[2], av[4];
#pragma unroll
      for (int mi = 0; mi < 2; ++mi)
        bp[mi] = *(const bf8*)(Pl + (W + mi * 16 + l16) * LDP + kk * 32 + quad * 8);
#pragma unroll
      for (int no = 0; no < 4; ++no) {
        const int row = no * 16 + l16;
        av[no] = *(const bf8*)(Vl + row * 128 + (((kk * 4 + quad) ^ l16) * 8));
      }
#pragma unroll
      for (int no = 0; no < 4; ++no)
#pragma unroll
        for (int mi = 0; mi < 2; ++mi)
          O2[no][mi] = mfma16(av[no], bp[mi], O2[no][mi]);
#pragma unroll
      for (int mi = 0; mi < 2; ++mi)
        lS[mi] = mfma16(ones, bp[mi], lS[mi]);
    }
  }

  // normalize and store O^T (C-layout: row=d=quad*4+rr contiguous, col=q=l16) -> packed 8B
#pragma unroll
  for (int mi = 0; mi < 2; ++mi) {
    const float inv = __builtin_amdgcn_rcpf(lS[mi][0]);  // all regs equal (ones rows)
    const int gm = bth * LL + qt * 128 + W + mi * 16 + l16;
    const size_t rowbase = (size_t)gm * DD + h * DH + quad * 4;
#pragma unroll
    for (int no = 0; no < 4; ++no) {
      ushort4 o4;
      o4.x = f2bf(O2[no][mi][0] * inv); o4.y = f2bf(O2[no][mi][1] * inv);
      o4.z = f2bf(O2[no][mi][2] * inv); o4.w = f2bf(O2[no][mi][3] * inv);
      *(ushort4*)(ow + rowbase + no * 16) = o4;
    }
  }
}

// ---------------- launch ----------------

extern "C" void kernel_launch(void* const* d_in, const int* in_sizes, int n_in,
                              void* d_out, int out_size, void* d_ws, size_t ws_size,
                              hipStream_t stream) {
  const float* x    = (const float*)d_in[0];  // (16, 512, 1024)
  const float* wqkv = (const float*)d_in[1];  // (1024, 3072)
  const float* rel  = (const float*)d_in[2];  // (255, 16)
  const float* wout = (const float*)d_in[3];  // (1024, 1024)
  const float* bout = (const float*)d_in[4];  // (1024,)
  float* out = (float*)d_out;

  char* ws = (char*)d_ws;
  unsigned short* xbf   = (unsigned short*)(ws);             // 16 MB  x as bf16 [8192][1024]
  unsigned short* wqkvT = (unsigned short*)(ws + 16777216);  //  6 MB  [3072][1024]
  unsigned short* woutT = (unsigned short*)(ws + 23068672);  //  2 MB  [1024][1024]
  unsigned short* qws   = (unsigned short*)(ws + 25165824);  // 16 MB  [256 bh][512][64]
  unsigned short* kws   = (unsigned short*)(ws + 41943040);  // 16 MB  [256 bh][512][64]
  unsigned short* vws   = (unsigned short*)(ws + 58720256);  // 16 MB  [256 bh][64][512]  (transposed)
  unsigned short* ows   = (unsigned short*)(ws + 75497472);  // 16 MB  [8192][1024]

  k_cvt<<<dim3(8192), dim3(256), 0, stream>>>(x, xbf);
  k_trans<<<dim3(96, 32), dim3(256), 0, stream>>>(wqkv, wqkvT, 1024, 3072);
  k_trans<<<dim3(32, 32), dim3(256), 0, stream>>>(wout, woutT, 1024, 1024);
  k_gemm_qkv<<<dim3(24, 64), dim3(256), 0, stream>>>(xbf, wqkvT, qws, kws, vws);
  k_attn<<<dim3(1024), dim3(256), 0, stream>>>(qws, kws, vws, rel, ows);
  k_gemm_out<<<dim3(8, 64), dim3(256), 0, stream>>>(ows, woutT, bout, out);
}

// Round 9
// 246.375 us; speedup vs baseline: 1.0459x; 1.0271x over previous
//
#include <hip/hip_runtime.h>
#include <cstddef>
#include <cstdint>

// Problem constants (B=2, T=8 -> BT=16), L=512, D=1024, H=16, dh=64, MAX_REL=128
#define BTN 16
#define LL 512
#define DD 1024
#define NH 16
#define DH 64

using bf8 = __attribute__((ext_vector_type(8))) short;          // 8 bf16 (4 VGPRs), MFMA operand
using fx4 = __attribute__((ext_vector_type(4))) float;          // MFMA accumulator

__device__ __forceinline__ unsigned short f2bf(float f) {
  unsigned int u = __float_as_uint(f);
  u += 0x7FFFu + ((u >> 16) & 1u);   // RNE
  return (unsigned short)(u >> 16);
}

__device__ __forceinline__ fx4 mfma16(bf8 a, bf8 b, fx4 c) {
  return __builtin_amdgcn_mfma_f32_16x16x32_bf16(a, b, c, 0, 0, 0);
}

// async global->LDS, 16B/lane, dest = wave-uniform base + lane*16
__device__ __forceinline__ void gld_lds16(const void* g, void* l) {
  __builtin_amdgcn_global_load_lds((const __attribute__((address_space(1))) void*)g,
                                   (__attribute__((address_space(3))) void*)l, 16, 0, 0);
}

// ---------------- fused prep kernel (cvt + both weight transposes in ONE launch) --------
// blocks [0,8192): x fp32->bf16;  [8192,11264): wqkv^T (1024x3072);  [11264,12288): wout^T.
__global__ __launch_bounds__(256) void k_prep(const float* __restrict__ x,
                                              unsigned short* __restrict__ xbf,
                                              const float* __restrict__ wqkv,
                                              unsigned short* __restrict__ wqkvT,
                                              const float* __restrict__ wout,
                                              unsigned short* __restrict__ woutT) {
  __shared__ float t[32][33];
  const int b = blockIdx.x;
  if (b < 8192) {
    const int i = b * 256 + threadIdx.x;
    const float4 v = ((const float4*)x)[i];
    ushort4 o;
    o.x = f2bf(v.x); o.y = f2bf(v.y); o.z = f2bf(v.z); o.w = f2bf(v.w);
    ((ushort4*)xbf)[i] = o;
    return;
  }
  const float* src; unsigned short* dst; int R, C, bx, by;
  if (b < 11264) { src = wqkv; dst = wqkvT; R = 1024; C = 3072; bx = (b - 8192) % 96; by = (b - 8192) / 96; }
  else           { src = wout; dst = woutT; R = 1024; C = 1024; bx = (b - 11264) & 31; by = (b - 11264) >> 5; }
  const int tx = threadIdx.x & 31, ty = threadIdx.x >> 5;
  const int c0 = bx * 32, r0 = by * 32;
  for (int i = ty; i < 32; i += 8)
    t[i][tx] = src[(size_t)(r0 + i) * C + c0 + tx];
  __syncthreads();
  for (int i = ty; i < 32; i += 8)
    dst[(size_t)(c0 + i) * R + r0 + tx] = f2bf(t[tx][i]);
}

// ---------------- GEMM core (C = A * B^T), A: Mx1024, B^T given as Nx1024 bf16 ----------------
// R4-PROVEN single-buffer structure. 128x128 block tile, BK=64, 4 waves in 2x2 of 64x64.
// LDS tiles UNPADDED [128][64] for global_load_lds; bank spread via XOR swizzle:
// LDS slot (row, s) holds global 16B-segment s ^ (row & 7).

__device__ __forceinline__ void gemm_core(const unsigned short* __restrict__ A,
                                          const unsigned short* __restrict__ B,
                                          unsigned short* Al, unsigned short* Bl,
                                          int m0, int n0, fx4 (&acc)[4][4]) {
  const int tid = threadIdx.x;
  const int lane = tid & 63, wave = tid >> 6;
  const int quad = lane >> 4, l16 = lane & 15;
  const int wr = (wave >> 1) * 64, wc = (wave & 1) * 64;
  const int rl = lane >> 3;                 // row within 8-row group
  const int sg = (lane & 7) ^ rl;           // swizzled global segment for this LDS slot
  const unsigned short* pa = A + (size_t)(m0 + wave * 32 + rl) * 1024 + sg * 8;
  const unsigned short* pb = B + (size_t)(n0 + wave * 32 + rl) * 1024 + sg * 8;
  unsigned short* la = Al + wave * 2048;    // 32 rows * 64 elems
  unsigned short* lb = Bl + wave * 2048;

  for (int kt = 0; kt < 1024; kt += 64) {
    __syncthreads();
#pragma unroll
    for (int i = 0; i < 4; ++i) {
      gld_lds16(pa + kt + i * 8 * 1024, la + i * 512);
      gld_lds16(pb + kt + i * 8 * 1024, lb + i * 512);
    }
    __syncthreads();
#pragma unroll
    for (int kk = 0; kk < 2; ++kk) {
      bf8 av[4], bv[4];
#pragma unroll
      for (int mi = 0; mi < 4; ++mi) {
        const int row = wr + mi * 16 + l16;
        av[mi] = *(const bf8*)(Al + row * 64 + (((kk * 4 + quad) ^ (l16 & 7)) * 8));
      }
#pragma unroll
      for (int nj = 0; nj < 4; ++nj) {
        const int row = wc + nj * 16 + l16;
        bv[nj] = *(const bf8*)(Bl + row * 64 + (((kk * 4 + quad) ^ (l16 & 7)) * 8));
      }
#pragma unroll
      for (int mi = 0; mi < 4; ++mi)
#pragma unroll
        for (int nj = 0; nj < 4; ++nj)
          acc[mi][nj] = mfma16(av[mi], bv[nj], acc[mi][nj]);
    }
  }
}

// QKV GEMM: x_bf (8192x1024) @ w_qkvT (3072x1024)^T -> scatter into q/k (bh-major) and vT.
__global__ __launch_bounds__(256, 4) void k_gemm_qkv(const unsigned short* __restrict__ xbf,
                                                     const unsigned short* __restrict__ wT,
                                                     unsigned short* __restrict__ qws,
                                                     unsigned short* __restrict__ kws,
                                                     unsigned short* __restrict__ vws) {
  __shared__ unsigned short Al[128 * 64];
  __shared__ unsigned short Bl[128 * 64];
  const int m0 = blockIdx.y * 128, n0 = blockIdx.x * 128;
  fx4 acc[4][4];
  const fx4 zero = {0.f, 0.f, 0.f, 0.f};
#pragma unroll
  for (int mi = 0; mi < 4; ++mi)
#pragma unroll
    for (int nj = 0; nj < 4; ++nj) acc[mi][nj] = zero;

  gemm_core(xbf, wT, Al, Bl, m0, n0, acc);

  const int lane = threadIdx.x & 63, wave = threadIdx.x >> 6;
  const int quad = lane >> 4, l16 = lane & 15;
  const int wr = (wave >> 1) * 64, wc = (wave & 1) * 64;
  const int which = n0 >> 10;  // 0=q, 1=k, 2=v (block-uniform: 1024 % 128 == 0)
#pragma unroll
  for (int mi = 0; mi < 4; ++mi)
#pragma unroll
    for (int nj = 0; nj < 4; ++nj) {
      const int gn = n0 + wc + nj * 16 + l16;
      const int rem = gn & 1023;
      const int hh = rem >> 6, dd = rem & 63;
#pragma unroll
      for (int rr = 0; rr < 4; ++rr) {
        const int gm = m0 + wr + mi * 16 + quad * 4 + rr;
        const int bth = gm >> 9, ll = gm & 511;
        const unsigned short v = f2bf(acc[mi][nj][rr]);
        const size_t bhh = (size_t)(bth * NH + hh);
        if (which == 0)      qws[(bhh * LL + ll) * DH + dd] = v;
        else if (which == 1) kws[(bhh * LL + ll) * DH + dd] = v;
        else                 vws[(bhh * DH + dd) * LL + ll] = v;  // V transposed [bh][d][l]
      }
    }
}

// Out projection: o_bf (8192x1024) @ w_outT (1024x1024)^T + b_out -> fp32 out.
__global__ __launch_bounds__(256, 4) void k_gemm_out(const unsigned short* __restrict__ obf,
                                                     const unsigned short* __restrict__ wT,
                                                     const float* __restrict__ bout,
                                                     float* __restrict__ out) {
  __shared__ unsigned short Al[128 * 64];
  __shared__ unsigned short Bl[128 * 64];
  const int m0 = blockIdx.y * 128, n0 = blockIdx.x * 128;
  fx4 acc[4][4];
  const fx4 zero = {0.f, 0.f, 0.f, 0.f};
#pragma unroll
  for (int mi = 0; mi < 4; ++mi)
#pragma unroll
    for (int nj = 0; nj < 4; ++nj) acc[mi][nj] = zero;

  gemm_core(obf, wT, Al, Bl, m0, n0, acc);

  const int lane = threadIdx.x & 63, wave = threadIdx.x >> 6;
  const int quad = lane >> 4, l16 = lane & 15;
  const int wr = (wave >> 1) * 64, wc = (wave & 1) * 64;
#pragma unroll
  for (int nj = 0; nj < 4; ++nj) {
    const int gn = n0 + wc + nj * 16 + l16;
    const float bb = bout[gn];
#pragma unroll
    for (int mi = 0; mi < 4; ++mi)
#pragma unroll
      for (int rr = 0; rr < 4; ++rr) {
        const int gm = m0 + wr + mi * 16 + quad * 4 + rr;
        out[(size_t)gm * 1024 + gn] = acc[mi][nj][rr] + bb;
      }
  }
}

// ---------------- flash attention with relative-position bias ----------------
// Transposed-score formulation (R7) + XCD co-location (R8).
// R9: 2-barrier st-iteration. KEY FACT: Pl is wave-private (PV B-frags read only rows
// W..W+32 written by the same wave), so no barrier is needed between P-write and P-read —
// in-wave lgkmcnt ordering suffices. The old 3rd barrier only protected Kl from the
// prefetch; barrier2 (after QK) already certifies all Kl reads retired. New schedule:
//   barrier1: drains K(st) prefetch; prior PV done (Vl free)
//   issue V(st)            -> lands during QK, drained at barrier2
//   QK (reads Kl)
//   barrier2: drains V(st); all Kl reads retired
//   issue K(st+1)          -> overlaps softmax + P-write + PV (longest window)
//   softmax -> P-write (wave-private) -> PV

#define LDP 140

__global__ __launch_bounds__(256, 2) void k_attn(const unsigned short* __restrict__ qw,
                                                 const unsigned short* __restrict__ kw,
                                                 const unsigned short* __restrict__ vw,
                                                 const float* __restrict__ rel,
                                                 unsigned short* __restrict__ ow) {
  __shared__ unsigned short Kl[128 * 64];
  __shared__ unsigned short Vl[64 * 128];
  __shared__ unsigned short Pl[128 * LDP];
  __shared__ float rell[255];

  const int tid = threadIdx.x;
  const int wave = tid >> 6, lane = tid & 63;
  const int quad = lane >> 4, l16 = lane & 15;
  const int bh = blockIdx.x & 255, qt = blockIdx.x >> 8;   // XCD co-location of a head's tiles
  const int bth = bh >> 4, h = bh & 15;
  const int W = wave * 32;

  if (tid < 255) rell[tid] = rel[tid * NH + h];

  // Q fragments (per-lane mapping identical for A- and B-operand use): row l16, k=quad*8+j
  bf8 qf[2][2];
  const size_t qbase = (size_t)bh * (LL * DH) + (size_t)(qt * 128 + W) * DH;
#pragma unroll
  for (int mi = 0; mi < 2; ++mi)
#pragma unroll
    for (int kk = 0; kk < 2; ++kk)
      qf[mi][kk] = *(const bf8*)(qw + qbase + (mi * 16 + l16) * DH + kk * 32 + quad * 8);

  fx4 O2[4][2];   // O^T tiles: [no over d][mi over q]
  fx4 lS[2];      // row sums per q (uniform over regs)
  const fx4 zero = {0.f, 0.f, 0.f, 0.f};
#pragma unroll
  for (int mi = 0; mi < 2; ++mi) {
    lS[mi] = zero;
#pragma unroll
    for (int no = 0; no < 4; ++no) O2[no][mi] = zero;
  }

  // staging lane mappings
  const int rk = lane >> 3, sgk = (lane & 7) ^ rk;     // K tile: 8 rows x 8 segs / instr
  const int rv = lane >> 4;                            // V tile: 4 rows x 16 segs / instr
  const unsigned short* kbase = kw + (size_t)bh * (LL * DH) + (size_t)(W + rk) * 64 + sgk * 8;
  const unsigned short* vbase = vw + (size_t)bh * (DH * LL);
  unsigned short* kdst = Kl + wave * 2048;
  unsigned short* vdst = Vl + wave * 2048;

  // prologue: stage K(0) async
#pragma unroll
  for (int i = 0; i < 4; ++i)
    gld_lds16(kbase + (size_t)(i * 8) * 64, kdst + i * 512);

  for (int st = 0; st < 4; ++st) {
    __syncthreads();  // barrier1: drains K(st); prior PV done (Vl free)

    // issue V(st) — lands during QK, drained at barrier2
#pragma unroll
    for (int i = 0; i < 4; ++i) {
      const int rowv = wave * 16 + i * 4 + rv;
      const int sgv = (lane & 15) ^ (rowv & 15);
      gld_lds16(vbase + (size_t)rowv * 512 + st * 128 + sgv * 8, vdst + i * 512);
    }

    // S^T = K Q^T  (tiles [mi over q][nj over s]; C-layout: row=s=quad*4+rr, col=q=l16)
    fx4 S[2][8];
#pragma unroll
    for (int mi = 0; mi < 2; ++mi)
#pragma unroll
      for (int nj = 0; nj < 8; ++nj) S[mi][nj] = zero;
#pragma unroll
    for (int kk = 0; kk < 2; ++kk) {
      bf8 ak[8];
#pragma unroll
      for (int nj = 0; nj < 8; ++nj) {
        const int row = nj * 16 + l16;
        ak[nj] = *(const bf8*)(Kl + row * 64 + (((kk * 4 + quad) ^ (l16 & 7)) * 8));
      }
#pragma unroll
      for (int mi = 0; mi < 2; ++mi)
#pragma unroll
        for (int nj = 0; nj < 8; ++nj)
          S[mi][nj] = mfma16(ak[nj], qf[mi][kk], S[mi][nj]);
    }

    __syncthreads();  // barrier2: drains V(st); all Kl reads retired

    // prefetch K(st+1) — overlaps softmax + P-write + PV
    if (st < 3) {
#pragma unroll
      for (int i = 0; i < 4; ++i)
        gld_lds16(kbase + (size_t)((st + 1) * 128 + i * 8) * 64, kdst + i * 512);
    }

    // ---- bias + exp (fixed-max softmax), specialized by tile distance ----
    // q = qt*128 + W + mi*16 + l16 ; s = st*128 + nj*16 + quad*4 + rr
    const int delta = qt - st;
    if (delta >= 2 || delta <= -2) {
      const float cb = (delta >= 2) ? rell[254] : rell[0];
#pragma unroll
      for (int mi = 0; mi < 2; ++mi)
#pragma unroll
        for (int nj = 0; nj < 8; ++nj)
#pragma unroll
          for (int rr = 0; rr < 4; ++rr)
            S[mi][nj][rr] = __expf(fmaf(S[mi][nj][rr], 0.125f, cb));
    } else if (delta == 0) {
#pragma unroll
      for (int mi = 0; mi < 2; ++mi) {
        const int base = W + mi * 16 + l16 - quad * 4 + 127;
#pragma unroll
        for (int nj = 0; nj < 8; ++nj) {
          const int bmn = base - nj * 16;
#pragma unroll
          for (int rr = 0; rr < 4; ++rr)
            S[mi][nj][rr] = __expf(fmaf(S[mi][nj][rr], 0.125f, rell[bmn - rr]));
        }
      }
    } else {  // |delta| == 1
#pragma unroll
      for (int mi = 0; mi < 2; ++mi) {
        const int base = delta * 128 + W + mi * 16 + l16 - quad * 4 + 127;
#pragma unroll
        for (int nj = 0; nj < 8; ++nj) {
          const int bmn = base - nj * 16;
#pragma unroll
          for (int rr = 0; rr < 4; ++rr) {
            int idx = bmn - rr;
            idx = idx < 0 ? 0 : (idx > 254 ? 254 : idx);
            S[mi][nj][rr] = __expf(fmaf(S[mi][nj][rr], 0.125f, rell[idx]));
          }
        }
      }
    }

    // P -> LDS row-major [q][s]; wave-private rows (W..W+32), no barrier needed
#pragma unroll
    for (int mi = 0; mi < 2; ++mi) {
      const int rowq = W + mi * 16 + l16;
#pragma unroll
      for (int nj = 0; nj < 8; ++nj) {
        ushort4 p4;
        p4.x = f2bf(S[mi][nj][0]); p4.y = f2bf(S[mi][nj][1]);
        p4.z = f2bf(S[mi][nj][2]); p4.w = f2bf(S[mi][nj][3]);
        *(ushort4*)(Pl + rowq * LDP + nj * 16 + quad * 4) = p4;
      }
    }

    // O^T += V^T P^T ; lS = mfma(ones, P^T)   (K-dim = 128 s, 4 MFMA k-steps)
    const bf8 ones = {0x3F80, 0x3F80, 0x3F80, 0x3F80, 0x3F80, 0x3F80, 0x3F80, 0x3F80};
#pragma unroll
    for (int kk = 0; kk < 4; ++kk) {
      bf8 bp[2], av[4];
#pragma unroll
      for (int mi = 0; mi < 2; ++mi)
        bp[mi] = *(const bf8*)(Pl + (W + mi * 16 + l16) * LDP + kk * 32 + quad * 8);
#pragma unroll
      for (int no = 0; no < 4; ++no) {
        const int row = no * 16 + l16;
        av[no] = *(const bf8*)(Vl + row * 128 + (((kk * 4 + quad) ^ l16) * 8));
      }
#pragma unroll
      for (int no = 0; no < 4; ++no)
#pragma unroll
        for (int mi = 0; mi < 2; ++mi)
          O2[no][mi] = mfma16(av[no], bp[mi], O2[no][mi]);
#pragma unroll
      for (int mi = 0; mi < 2; ++mi)
        lS[mi] = mfma16(ones, bp[mi], lS[mi]);
    }
  }

  // normalize and store O^T (C-layout: row=d=quad*4+rr contiguous, col=q=l16) -> packed 8B
#pragma unroll
  for (int mi = 0; mi < 2; ++mi) {
    const float inv = __builtin_amdgcn_rcpf(lS[mi][0]);  // all regs equal (ones rows)
    const int gm = bth * LL + qt * 128 + W + mi * 16 + l16;
    const size_t rowbase = (size_t)gm * DD + h * DH + quad * 4;
#pragma unroll
    for (int no = 0; no < 4; ++no) {
      ushort4 o4;
      o4.x = f2bf(O2[no][mi][0] * inv); o4.y = f2bf(O2[no][mi][1] * inv);
      o4.z = f2bf(O2[no][mi][2] * inv); o4.w = f2bf(O2[no][mi][3] * inv);
      *(ushort4*)(ow + rowbase + no * 16) = o4;
    }
  }
}

// ---------------- launch ----------------

extern "C" void kernel_launch(void* const* d_in, const int* in_sizes, int n_in,
                              void* d_out, int out_size, void* d_ws, size_t ws_size,
                              hipStream_t stream) {
  const float* x    = (const float*)d_in[0];  // (16, 512, 1024)
  const float* wqkv = (const float*)d_in[1];  // (1024, 3072)
  const float* rel  = (const float*)d_in[2];  // (255, 16)
  const float* wout = (const float*)d_in[3];  // (1024, 1024)
  const float* bout = (const float*)d_in[4];  // (1024,)
  float* out = (float*)d_out;

  char* ws = (char*)d_ws;
  unsigned short* xbf   = (unsigned short*)(ws);             // 16 MB  x as bf16 [8192][1024]
  unsigned short* wqkvT = (unsigned short*)(ws + 16777216);  //  6 MB  [3072][1024]
  unsigned short* woutT = (unsigned short*)(ws + 23068672);  //  2 MB  [1024][1024]
  unsigned short* qws   = (unsigned short*)(ws + 25165824);  // 16 MB  [256 bh][512][64]
  unsigned short* kws   = (unsigned short*)(ws + 41943040);  // 16 MB  [256 bh][512][64]
  unsigned short* vws   = (unsigned short*)(ws + 58720256);  // 16 MB  [256 bh][64][512]  (transposed)
  unsigned short* ows   = (unsigned short*)(ws + 75497472);  // 16 MB  [8192][1024]

  k_prep<<<dim3(12288), dim3(256), 0, stream>>>(x, xbf, wqkv, wqkvT, wout, woutT);
  k_gemm_qkv<<<dim3(24, 64), dim3(256), 0, stream>>>(xbf, wqkvT, qws, kws, vws);
  k_attn<<<dim3(1024), dim3(256), 0, stream>>>(qws, kws, vws, rel, ows);
  k_gemm_out<<<dim3(8, 64), dim3(256), 0, stream>>>(ows, woutT, bout, out);
}